// Round 8
// baseline (716.445 us; speedup 1.0000x reference)
//
#include <hip/hip_runtime.h>
#include <hip/hip_bf16.h>
#include <math.h>

// Problem constants
#define NC 3
#define NK 64
#define KK 3
#define K2 9
#define PAD 1
#define SCALE 4
#define S2 16
#define MID 4
#define B 4
#define H 128
#define W 128
#define HW (H*W)          // 16384
#define CIN 67            // NK + NC
#define OUT_HW (H*SCALE)  // 512

// im2col GEMM geometry: K per tap padded 67->72; total 9*72=648, tail-padded
// to 672 = 21*32 (tail multiplied by A-side zeros; 0xAA ws poison is finite
// bf16 so 0*garbage = 0).
#define KTAP 72
#define KTOT 672
#define NKS 21

typedef short bf16x8 __attribute__((ext_vector_type(8)));
typedef float f32x4 __attribute__((ext_vector_type(4)));

__device__ __forceinline__ float fast_sigmoid(float v) { return 1.f / (1.f + __expf(-v)); }
__device__ __forceinline__ float fast_tanh(float v) { return 2.f / (1.f + __expf(-2.f * v)) - 1.f; }

// fp32 -> bf16 round-to-nearest-even
__device__ __forceinline__ unsigned short f2bf(float f) {
    unsigned int u = __float_as_uint(f);
    unsigned int r = (u + 0x7FFFu + ((u >> 16) & 1u)) >> 16;
    return (unsigned short)r;
}

// load a zero-padded 3x3 patch of one channel plane (HxW) at (y,x)
__device__ __forceinline__ void load_patch(const float* __restrict__ xc, int y, int x, float* p) {
#pragma unroll
    for (int dy = -1; dy <= 1; dy++) {
#pragma unroll
        for (int dx = -1; dx <= 1; dx++) {
            int yy = y + dy, xx = x + dx;
            float v = (yy >= 0 && yy < H && xx >= 0 && xx < W) ? xc[yy * W + xx] : 0.f;
            p[(dy + 1) * 3 + (dx + 1)] = v;
        }
    }
}

// ---------------------------------------------------------------------------
// ConvLSTM with h=0,c=0: only first NC input channels of lstm_w matter;
// f-gate irrelevant (c_prev=0). blockIdx.y selects a 16-channel gate group.
// ---------------------------------------------------------------------------
__global__ __launch_bounds__(256) void k_lstm(const float* __restrict__ X,
                                              const float* __restrict__ lw,
                                              const float* __restrict__ lb,
                                              float* __restrict__ xcatA,
                                              float* __restrict__ hid_out,
                                              float* __restrict__ cell_out) {
    int t = blockIdx.x * blockDim.x + threadIdx.x;
    int b = t >> 14, hw = t & (HW - 1), y = hw >> 7, x = hw & (W - 1);
    int nk0 = blockIdx.y * 16;
    float p[NC][9];
#pragma unroll
    for (int c = 0; c < NC; c++) load_patch(X + (b * NC + c) * HW, y, x, p[c]);
    float* xc = xcatA + (size_t)b * CIN * HW;
    for (int i = 0; i < 16; i++) {
        int nk = nk0 + i;
        float gi = lb[nk], go = lb[2 * NK + nk], gg = lb[3 * NK + nk];
#pragma unroll
        for (int c = 0; c < NC; c++) {
            const float* wi = lw + (size_t)(nk) * (CIN * 9) + c * 9;
            const float* wo = lw + (size_t)(2 * NK + nk) * (CIN * 9) + c * 9;
            const float* wg = lw + (size_t)(3 * NK + nk) * (CIN * 9) + c * 9;
#pragma unroll
            for (int tt = 0; tt < 9; tt++) {
                gi += p[c][tt] * wi[tt];
                go += p[c][tt] * wo[tt];
                gg += p[c][tt] * wg[tt];
            }
        }
        float cv = fast_sigmoid(gi) * fast_tanh(gg);
        float hv = fast_sigmoid(go) * fast_tanh(cv);
        xc[nk * HW + hw] = hv;
        hid_out[(b * NK + nk) * HW + hw] = hv;
        cell_out[(b * NK + nk) * HW + hw] = cv;
    }
}

// copy lr (X) into channels 64..66 of both xcat buffers
__global__ __launch_bounds__(256) void k_copy_lr(const float* __restrict__ X,
                                                 float* __restrict__ xcatA,
                                                 float* __restrict__ xcatB) {
    int t = blockIdx.x * blockDim.x + threadIdx.x;
    int b = t >> 14, hw = t & (HW - 1);
#pragma unroll
    for (int c = 0; c < NC; c++) {
        float v = X[(b * NC + c) * HW + hw];
        xcatA[(size_t)b * CIN * HW + (NK + c) * HW + hw] = v;
        xcatB[(size_t)b * CIN * HW + (NK + c) * HW + hw] = v;
    }
}

// ---------------------------------------------------------------------------
// Prepack deform weights dw[o<64][c<67][k<9] into MFMA A-fragment order, bf16.
// Fragment g = ks*4+mt (ks<21, mt<4): apk[g*512 + lane*8 + j] = A[m][k] with
// m = mt*16+(lane&15), k = ks*32+(lane>>4)*8+j; A[m][k] = w[m][c][tap] for
// k = tap*KTAP+c (c<67, k<648), else 0. grid 84 x 512.
// ---------------------------------------------------------------------------
__global__ void k_prepA(const float* __restrict__ w, unsigned short* __restrict__ apk) {
    int g = blockIdx.x;            // ks*4+mt
    int tid = threadIdx.x;         // 0..511
    int lane = tid >> 3, j = tid & 7;
    int mt = g & 3, ks = g >> 2;
    int o = mt * 16 + (lane & 15);
    int k = ks * 32 + ((lane >> 4) << 3) + j;
    int tap = k / KTAP, c = k - tap * KTAP;
    float val = (k < 9 * KTAP && c < CIN) ? w[(size_t)o * (CIN * 9) + c * 9 + tap] : 0.f;
    apk[(size_t)g * 512 + tid] = f2bf(val);
}

// ---------------------------------------------------------------------------
// Offset + mask convs, c-split. Block = 256 threads = 64 pixels; the 4 waves
// partition the 67 input channels (16/17/17/17); each wave accumulates all 27
// outputs in VGPRs (static indices only). LDS reduction, then offsets stored
// raw and mask as 2*sigmoid. XCD-contiguous strip swizzle.
// ---------------------------------------------------------------------------
__global__ __launch_bounds__(256, 4) void k_offmask(const float* __restrict__ xcat,
                                                    const float* __restrict__ ow,
                                                    const float* __restrict__ ob,
                                                    const float* __restrict__ mw,
                                                    const float* __restrict__ mb,
                                                    float* __restrict__ offb,
                                                    float* __restrict__ maskb) {
    __shared__ float red[4 * 27 * 64];  // 27648 B
    int lane = threadIdx.x & 63;
    int wid = __builtin_amdgcn_readfirstlane((int)(threadIdx.x >> 6));
    int blk = blockIdx.x;
    int sg = (blk & 7) * 128 + (blk >> 3);  // XCD-contiguous strip id
    int b = sg >> 8;
    int hwbase = (sg & 255) * 64;
    int hw = hwbase + lane, y = hw >> 7, x = hw & (W - 1);
    int c0 = (CIN * wid) >> 2, c1 = (CIN * (wid + 1)) >> 2;

    float acc[27];
#pragma unroll
    for (int i = 0; i < 27; i++) acc[i] = 0.f;
    const float* xb = xcat + (size_t)b * CIN * HW;
    for (int c = c0; c < c1; c++) {
        float p[9];
        load_patch(xb + c * HW, y, x, p);
#pragma unroll
        for (int oc = 0; oc < 18; oc++) {
            const float* w = ow + (size_t)oc * (CIN * 9) + c * 9;
#pragma unroll
            for (int tt = 0; tt < 9; tt++) acc[oc] += p[tt] * w[tt];
        }
#pragma unroll
        for (int oc = 0; oc < 9; oc++) {
            const float* w = mw + (size_t)oc * (CIN * 9) + c * 9;
#pragma unroll
            for (int tt = 0; tt < 9; tt++) acc[18 + oc] += p[tt] * w[tt];
        }
    }
#pragma unroll
    for (int j = 0; j < 27; j++) red[(wid * 27 + j) * 64 + lane] = acc[j];
    __syncthreads();
    for (int idx = threadIdx.x; idx < 27 * 64; idx += 256) {
        int j = idx >> 6, px = idx & 63;
        float s = red[j * 64 + px] + red[(27 + j) * 64 + px]
                + red[(54 + j) * 64 + px] + red[(81 + j) * 64 + px];
        if (j < 18) {
            offb[(b * 18 + j) * HW + hwbase + px] = s + ob[j];
        } else {
            int mj = j - 18;
            maskb[(b * 9 + mj) * HW + hwbase + px] = 2.f * fast_sigmoid(s + mb[mj]);
        }
    }
}

// ---------------------------------------------------------------------------
// im2col for deform: materialize vcol[row=global_px][k] bf16 (k = tap*72+c),
// row stride KTOT=672 shorts (1344 B, 16B-aligned). Block = (strip, tap):
// 4 waves partition c (18 each; c>=67 -> 0). Bilinear gather per (tap,px),
// LDS transpose tile [64px][74] (odd dword stride -> conflict-free), then
// coalesced uint writes of the 72-short tap segment per row.
// ---------------------------------------------------------------------------
__global__ __launch_bounds__(256) void k_im2col(const float* __restrict__ xcat,
                                                const float* __restrict__ offb,
                                                const float* __restrict__ maskb,
                                                unsigned short* __restrict__ vcol) {
    __shared__ unsigned short vbuf[64 * 74];  // 9472 B
    int lane = threadIdx.x & 63;
    int wid = threadIdx.x >> 6;
    int tap = blockIdx.y;
    int blk = blockIdx.x;
    int sg = (blk & 7) * 128 + (blk >> 3);  // XCD-contiguous strip id
    int b = sg >> 8;
    int hwbase = (sg & 255) * 64;
    int hw = hwbase + lane;
    int y = hw >> 7, x = hw & (W - 1);

    // bilinear setup for (tap, px)
    int ky = tap / 3, kx = tap - ky * 3;
    float offy = offb[(b * 18 + 2 * tap) * HW + hw];
    float offx = offb[(b * 18 + 2 * tap + 1) * HW + hw];
    float m = maskb[(b * 9 + tap) * HW + hw];
    float py = (float)(y + ky - 1) + offy;
    float px_ = (float)(x + kx - 1) + offx;
    float fy = floorf(py), fx = floorf(px_);
    float wy = py - fy, wx = px_ - fx;
    int y0 = (int)fy, x0 = (int)fx;
    int y1 = y0 + 1, x1 = x0 + 1;
    float vy0 = (y0 >= 0 && y0 <= H - 1) ? 1.f : 0.f;
    float vy1 = (y1 >= 0 && y1 <= H - 1) ? 1.f : 0.f;
    float vx0 = (x0 >= 0 && x0 <= W - 1) ? 1.f : 0.f;
    float vx1 = (x1 >= 0 && x1 <= W - 1) ? 1.f : 0.f;
    int yc0 = min(max(y0, 0), H - 1), yc1 = min(max(y1, 0), H - 1);
    int xc0 = min(max(x0, 0), W - 1), xc1 = min(max(x1, 0), W - 1);
    float a00 = (1.f - wy) * (1.f - wx) * m * vy0 * vx0;
    float a01 = (1.f - wy) * wx * m * vy0 * vx1;
    float a10 = wy * (1.f - wx) * m * vy1 * vx0;
    float a11 = wy * wx * m * vy1 * vx1;
    int j00 = yc0 * W + xc0, j01 = yc0 * W + xc1;
    int j10 = yc1 * W + xc0, j11 = yc1 * W + xc1;

    const float* xb = xcat + (size_t)b * CIN * HW;
    int c0 = wid * 18;
#pragma unroll 3
    for (int i = 0; i < 18; i++) {
        int c = c0 + i;
        float v = 0.f;
        if (c < CIN) {
            const float* xc = xb + c * HW;
            v = a00 * xc[j00] + a01 * xc[j01] + a10 * xc[j10] + a11 * xc[j11];
        }
        vbuf[lane * 74 + c] = f2bf(v);
    }
    __syncthreads();

    // write out: row px gets 72 shorts = 36 uints at vcol[(sg*64+px)*672 + tap*72]
    const unsigned int* vb = (const unsigned int*)vbuf;
    unsigned int* dst = (unsigned int*)vcol;
    for (int i = threadIdx.x; i < 64 * 36; i += 256) {
        int px = i / 36, u = i - px * 36;
        dst[(size_t)(sg * 64 + px) * (KTOT / 2) + tap * (KTAP / 2) + u] = vb[px * 37 + u];
    }
}

// ---------------------------------------------------------------------------
// Deform GEMM: C[64 o][64 px] per strip. Block = 256 thr = 4 waves; wave =
// N-tile nt (16 px). B-frags are direct 16B global loads from vcol (lane's
// 8 k-values contiguous); A-frags from apk (shared across waves -> L1).
// 84 MFMAs/wave, no LDS, no barriers. XCD-contiguous strip swizzle.
// ---------------------------------------------------------------------------
__global__ __launch_bounds__(256) void k_gemmD(const unsigned short* __restrict__ vcol,
                                               const unsigned short* __restrict__ apk,
                                               const float* __restrict__ bias,
                                               float* __restrict__ xout) {
    int lane = threadIdx.x & 63;
    int nt = __builtin_amdgcn_readfirstlane((int)(threadIdx.x >> 6));
    int blk = blockIdx.x;
    int sg = (blk & 7) * 128 + (blk >> 3);  // XCD-contiguous strip id
    int b = sg >> 8;
    int hwbase = (sg & 255) * 64;
    int n = lane & 15, q = lane >> 4;

    const unsigned short* brow = vcol + (size_t)(sg * 64 + nt * 16 + n) * KTOT + q * 8;
    const unsigned short* arow = apk + (size_t)lane * 8;

    f32x4 acc[4];
#pragma unroll
    for (int mt = 0; mt < 4; mt++) { f32x4 z = {0.f, 0.f, 0.f, 0.f}; acc[mt] = z; }

#pragma unroll
    for (int ks = 0; ks < NKS; ks++) {
        bf16x8 bf = *(const bf16x8*)(brow + ks * 32);
#pragma unroll
        for (int mt = 0; mt < 4; mt++) {
            bf16x8 af = *(const bf16x8*)(arow + (size_t)(ks * 4 + mt) * 512);
            acc[mt] = __builtin_amdgcn_mfma_f32_16x16x32_bf16(af, bf, acc[mt], 0, 0, 0);
        }
    }

    // D[row=q*4+r][col=n] per M-tile
    float* xo = xout + (size_t)b * CIN * HW + hwbase;
#pragma unroll
    for (int mt = 0; mt < 4; mt++) {
#pragma unroll
        for (int r = 0; r < 4; r++) {
            int o = mt * 16 + q * 4 + r;
            xo[(size_t)o * HW + nt * 16 + n] = acc[mt][r] + bias[o];
        }
    }
}

// final 3-channel conv over 67-channel concat; blockIdx.y = output channel
__global__ __launch_bounds__(256) void k_conv3(const float* __restrict__ xcat,
                                               const float* __restrict__ cw,
                                               const float* __restrict__ cb,
                                               float* __restrict__ y3) {
    int t = blockIdx.x * blockDim.x + threadIdx.x;
    int b = t >> 14, hw = t & (HW - 1), y = hw >> 7, x = hw & (W - 1);
    int oc = blockIdx.y;
    float acc = cb[oc];
    const float* xb = xcat + (size_t)b * CIN * HW;
    const float* wb = cw + (size_t)oc * (CIN * 9);
    for (int c = 0; c < CIN; c++) {
        float p[9];
        load_patch(xb + c * HW, y, x, p);
        const float* w = wb + c * 9;
#pragma unroll
        for (int tt = 0; tt < 9; tt++) acc += p[tt] * w[tt];
    }
    y3[(b * NC + oc) * HW + hw] = acc;
}

// global average pool: one block per (b,c)
__global__ __launch_bounds__(256) void k_pool(const float* __restrict__ y3,
                                              float* __restrict__ pooled) {
    int bc = blockIdx.x;  // 0..11
    const float* p = y3 + (size_t)bc * HW;
    float s = 0.f;
    for (int i = threadIdx.x; i < HW; i += 256) s += p[i];
    __shared__ float red[256];
    red[threadIdx.x] = s;
    __syncthreads();
    for (int off = 128; off > 0; off >>= 1) {
        if (threadIdx.x < off) red[threadIdx.x] += red[threadIdx.x + off];
        __syncthreads();
    }
    if (threadIdx.x == 0) pooled[bc] = red[0] / (float)HW;
}

// tiny per-branch channel MLP -> ch[b,s,c,k]
__global__ void k_ch(const float* __restrict__ pooled, const float* __restrict__ w1,
                     const float* __restrict__ b1, const float* __restrict__ w2,
                     const float* __restrict__ b2, float* __restrict__ chbuf) {
    int t = threadIdx.x;
    if (t >= B * S2) return;
    int b = t >> 4, s = t & 15;
    float h1[MID];
#pragma unroll
    for (int m = 0; m < MID; m++) {
        float a = b1[s * MID + m];
#pragma unroll
        for (int c = 0; c < NC; c++) a += pooled[b * NC + c] * w1[(s * MID + m) * NC + c];
        h1[m] = fmaxf(a, 0.f);
    }
    for (int kk = 0; kk < NC * K2; kk++) {
        float a = b2[s * (NC * K2) + kk];
#pragma unroll
        for (int m = 0; m < MID; m++) a += h1[m] * w2[(s * (NC * K2) + kk) * MID + m];
        chbuf[(b * S2 + s) * (NC * K2) + kk] = a;
    }
}

// ---------------------------------------------------------------------------
// Fused DDF upsample: spatial-filter conv + dynamic combine + pixel_shuffle
// + clip. blockIdx.y selects 4 of the 16 branches; that quarter of sp_w/sp_b
// and ch staged in LDS (block is single-batch).
// ---------------------------------------------------------------------------
__global__ __launch_bounds__(256) void k_ddf(const float* __restrict__ y3,
                                             const float* __restrict__ spw,
                                             const float* __restrict__ spb,
                                             const float* __restrict__ chbuf,
                                             float* __restrict__ out) {
    __shared__ float s_spw[4 * K2 * NC * 9];  // 972
    __shared__ float s_spb[4 * K2];           // 36
    __shared__ float s_ch[4 * NC * K2];       // 108
    int t = blockIdx.x * blockDim.x + threadIdx.x;
    int b = t >> 14, hw = t & (HW - 1), y = hw >> 7, x = hw & (W - 1);
    int s0 = blockIdx.y * 4;
    for (int i = threadIdx.x; i < 4 * K2 * NC * 9; i += 256) s_spw[i] = spw[s0 * K2 * NC * 9 + i];
    if (threadIdx.x < 4 * K2) s_spb[threadIdx.x] = spb[s0 * K2 + threadIdx.x];
    if (threadIdx.x < 4 * NC * K2) s_ch[threadIdx.x] = chbuf[b * (S2 * NC * K2) + s0 * NC * K2 + threadIdx.x];
    __syncthreads();
    float p[NC][9];
#pragma unroll
    for (int c = 0; c < NC; c++) load_patch(y3 + (b * NC + c) * HW, y, x, p[c]);
#pragma unroll
    for (int si = 0; si < 4; si++) {
        int s = s0 + si;
        float spv[K2];
#pragma unroll
        for (int k = 0; k < K2; k++) {
            float a = s_spb[si * K2 + k];
            const float* w = s_spw + (si * K2 + k) * (NC * 9);
#pragma unroll
            for (int c = 0; c < NC; c++)
#pragma unroll
                for (int tt = 0; tt < 9; tt++) a += p[c][tt] * w[c * 9 + tt];
            spv[k] = a;
        }
        int sy = s >> 2, sx = s & 3;
#pragma unroll
        for (int c = 0; c < NC; c++) {
            float a = 0.f;
            const float* chp = s_ch + (si * NC + c) * K2;
#pragma unroll
            for (int k = 0; k < K2; k++) a += p[c][k] * (chp[k] + spv[k]);
            a = fminf(fmaxf(a, 0.f), 255.f);
            out[((size_t)(b * NC + c) * OUT_HW + (y * SCALE + sy)) * OUT_HW + (x * SCALE + sx)] = a;
        }
    }
}

extern "C" void kernel_launch(void* const* d_in, const int* in_sizes, int n_in,
                              void* d_out, int out_size, void* d_ws, size_t ws_size,
                              hipStream_t stream) {
    const float* X = (const float*)d_in[0];
    const float* lstm_w = (const float*)d_in[1];
    const float* lstm_b = (const float*)d_in[2];
    const float* ow[3] = {(const float*)d_in[3], (const float*)d_in[9], (const float*)d_in[15]};
    const float* ob[3] = {(const float*)d_in[4], (const float*)d_in[10], (const float*)d_in[16]};
    const float* mw[3] = {(const float*)d_in[5], (const float*)d_in[11], (const float*)d_in[17]};
    const float* mb[3] = {(const float*)d_in[6], (const float*)d_in[12], (const float*)d_in[18]};
    const float* dw[3] = {(const float*)d_in[7], (const float*)d_in[13], (const float*)d_in[19]};
    const float* db[3] = {(const float*)d_in[8], (const float*)d_in[14], (const float*)d_in[20]};
    const float* conv_w = (const float*)d_in[21];
    const float* conv_b = (const float*)d_in[22];
    const float* sp_w = (const float*)d_in[23];
    const float* sp_b = (const float*)d_in[24];
    const float* ch_w1 = (const float*)d_in[25];
    const float* ch_b1 = (const float*)d_in[26];
    const float* ch_w2 = (const float*)d_in[27];
    const float* ch_b2 = (const float*)d_in[28];

    float* out = (float*)d_out;
    const size_t OUT_IMG = (size_t)B * NC * OUT_HW * OUT_HW;  // 3145728
    const size_t HIDSZ = (size_t)B * NK * HW;                 // 4194304
    float* hid_out = out + OUT_IMG;
    float* cell_out = out + OUT_IMG + HIDSZ;

    float* ws = (float*)d_ws;
    const size_t XCAT = (size_t)B * CIN * HW;  // 4390912
    float* xcatA = ws;            ws += XCAT;
    float* xcatB = ws;            ws += XCAT;
    float* offb = ws;             ws += (size_t)B * 18 * HW;
    float* maskb = ws;            ws += (size_t)B * 9 * HW;
    unsigned short* apk[3];
    for (int i = 0; i < 3; i++) { apk[i] = (unsigned short*)ws; ws += 84 * 512 / 2; }
    float* y3 = ws;               ws += (size_t)B * NC * HW;
    float* pooled = ws;           ws += 16;
    float* chbuf = ws;            ws += (size_t)B * S2 * NC * K2;
    unsigned short* vcol = (unsigned short*)ws;
    ws += (size_t)B * 256 * 64 * KTOT / 2;  // 88 MB bf16 im2col buffer

    dim3 blk(256);
    dim3 g1(B * HW / 256);        // 256 blocks
    dim3 g4(B * HW / 256, 4);
    dim3 g3(B * HW / 256, 3);
    dim3 gd(B * HW / 64);         // 1024 strips
    dim3 gi(B * HW / 64, 9);      // strips x taps for im2col

    k_lstm<<<g4, blk, 0, stream>>>(X, lstm_w, lstm_b, xcatA, hid_out, cell_out);
    k_copy_lr<<<g1, blk, 0, stream>>>(X, xcatA, xcatB);
    for (int i = 0; i < 3; i++)
        k_prepA<<<dim3(84), dim3(512), 0, stream>>>(dw[i], apk[i]);

    // layer 1: xcatA -> xcatB
    k_offmask<<<gd, blk, 0, stream>>>(xcatA, ow[0], ob[0], mw[0], mb[0], offb, maskb);
    k_im2col<<<gi, blk, 0, stream>>>(xcatA, offb, maskb, vcol);
    k_gemmD<<<gd, blk, 0, stream>>>(vcol, apk[0], db[0], xcatB);
    // layer 2: xcatB -> xcatA
    k_offmask<<<gd, blk, 0, stream>>>(xcatB, ow[1], ob[1], mw[1], mb[1], offb, maskb);
    k_im2col<<<gi, blk, 0, stream>>>(xcatB, offb, maskb, vcol);
    k_gemmD<<<gd, blk, 0, stream>>>(vcol, apk[1], db[1], xcatA);
    // layer 3: xcatA -> xcatB
    k_offmask<<<gd, blk, 0, stream>>>(xcatA, ow[2], ob[2], mw[2], mb[2], offb, maskb);
    k_im2col<<<gi, blk, 0, stream>>>(xcatA, offb, maskb, vcol);
    k_gemmD<<<gd, blk, 0, stream>>>(vcol, apk[2], db[2], xcatB);

    k_conv3<<<g3, blk, 0, stream>>>(xcatB, conv_w, conv_b, y3);
    k_pool<<<dim3(B * NC), blk, 0, stream>>>(y3, pooled);
    k_ch<<<dim3(1), dim3(64), 0, stream>>>(pooled, ch_w1, ch_b1, ch_w2, ch_b2, chbuf);
    k_ddf<<<g4, blk, 0, stream>>>(y3, sp_w, sp_b, chbuf, out);
}

// Round 9
// 687.135 us; speedup vs baseline: 1.0427x; 1.0427x over previous
//
#include <hip/hip_runtime.h>
#include <hip/hip_bf16.h>
#include <math.h>

// Problem constants
#define NC 3
#define NK 64
#define KK 3
#define K2 9
#define PAD 1
#define SCALE 4
#define S2 16
#define MID 4
#define B 4
#define H 128
#define W 128
#define HW (H*W)          // 16384
#define CIN 67            // NK + NC
#define OUT_HW (H*SCALE)  // 512

typedef short bf16x8 __attribute__((ext_vector_type(8)));
typedef float f32x4 __attribute__((ext_vector_type(4)));

__device__ __forceinline__ float fast_sigmoid(float v) { return 1.f / (1.f + __expf(-v)); }
__device__ __forceinline__ float fast_tanh(float v) { return 2.f / (1.f + __expf(-2.f * v)) - 1.f; }

// fp32 -> bf16 round-to-nearest-even
__device__ __forceinline__ unsigned short f2bf(float f) {
    unsigned int u = __float_as_uint(f);
    unsigned int r = (u + 0x7FFFu + ((u >> 16) & 1u)) >> 16;
    return (unsigned short)r;
}

// load a zero-padded 3x3 patch of one channel plane (HxW) at (y,x)
__device__ __forceinline__ void load_patch(const float* __restrict__ xc, int y, int x, float* p) {
#pragma unroll
    for (int dy = -1; dy <= 1; dy++) {
#pragma unroll
        for (int dx = -1; dx <= 1; dx++) {
            int yy = y + dy, xx = x + dx;
            float v = (yy >= 0 && yy < H && xx >= 0 && xx < W) ? xc[yy * W + xx] : 0.f;
            p[(dy + 1) * 3 + (dx + 1)] = v;
        }
    }
}

// ---------------------------------------------------------------------------
// ConvLSTM with h=0,c=0: only first NC input channels of lstm_w matter;
// f-gate irrelevant (c_prev=0). blockIdx.y selects a 16-channel gate group.
// ---------------------------------------------------------------------------
__global__ __launch_bounds__(256) void k_lstm(const float* __restrict__ X,
                                              const float* __restrict__ lw,
                                              const float* __restrict__ lb,
                                              float* __restrict__ xcatA,
                                              float* __restrict__ hid_out,
                                              float* __restrict__ cell_out) {
    int t = blockIdx.x * blockDim.x + threadIdx.x;
    int b = t >> 14, hw = t & (HW - 1), y = hw >> 7, x = hw & (W - 1);
    int nk0 = blockIdx.y * 16;
    float p[NC][9];
#pragma unroll
    for (int c = 0; c < NC; c++) load_patch(X + (b * NC + c) * HW, y, x, p[c]);
    float* xc = xcatA + (size_t)b * CIN * HW;
    for (int i = 0; i < 16; i++) {
        int nk = nk0 + i;
        float gi = lb[nk], go = lb[2 * NK + nk], gg = lb[3 * NK + nk];
#pragma unroll
        for (int c = 0; c < NC; c++) {
            const float* wi = lw + (size_t)(nk) * (CIN * 9) + c * 9;
            const float* wo = lw + (size_t)(2 * NK + nk) * (CIN * 9) + c * 9;
            const float* wg = lw + (size_t)(3 * NK + nk) * (CIN * 9) + c * 9;
#pragma unroll
            for (int tt = 0; tt < 9; tt++) {
                gi += p[c][tt] * wi[tt];
                go += p[c][tt] * wo[tt];
                gg += p[c][tt] * wg[tt];
            }
        }
        float cv = fast_sigmoid(gi) * fast_tanh(gg);
        float hv = fast_sigmoid(go) * fast_tanh(cv);
        xc[nk * HW + hw] = hv;
        hid_out[(b * NK + nk) * HW + hw] = hv;
        cell_out[(b * NK + nk) * HW + hw] = cv;
    }
}

// copy lr (X) into channels 64..66 of both xcat buffers
__global__ __launch_bounds__(256) void k_copy_lr(const float* __restrict__ X,
                                                 float* __restrict__ xcatA,
                                                 float* __restrict__ xcatB) {
    int t = blockIdx.x * blockDim.x + threadIdx.x;
    int b = t >> 14, hw = t & (HW - 1);
#pragma unroll
    for (int c = 0; c < NC; c++) {
        float v = X[(b * NC + c) * HW + hw];
        xcatA[(size_t)b * CIN * HW + (NK + c) * HW + hw] = v;
        xcatB[(size_t)b * CIN * HW + (NK + c) * HW + hw] = v;
    }
}

// ---------------------------------------------------------------------------
// Prepack deform weights dw[o<64][c<67][k<9] into MFMA A-fragment order, bf16:
// frag g = (tap*3+ks)*4+mt: apk[g*512 + lane*8 + j] = A[m][kc] with
// m = mt*16+(lane&15), kc = ks*32+(lane>>4)*8+j (per-tap channel; 0 if >=67).
// grid 108 blocks x 512 threads.
// ---------------------------------------------------------------------------
__global__ void k_prepA(const float* __restrict__ w, unsigned short* __restrict__ apk) {
    int g = blockIdx.x;            // (tap*3+ks)*4+mt
    int tid = threadIdx.x;         // 0..511
    int lane = tid >> 3, j = tid & 7;
    int mt = g & 3, r = g >> 2;    // r = tap*3+ks
    int ks = r % 3, tap = r / 3;
    int o = mt * 16 + (lane & 15);
    int c = ks * 32 + ((lane >> 4) << 3) + j;
    float val = (c < CIN) ? w[(size_t)o * (CIN * 9) + c * 9 + tap] : 0.f;
    apk[(size_t)g * 512 + tid] = f2bf(val);
}

// ---------------------------------------------------------------------------
// Offset + mask convs, c-split. Block = 256 threads = 64 pixels; the 4 waves
// partition the 67 input channels (16/17/17/17); each wave accumulates all 27
// outputs in VGPRs (static indices only). LDS reduction, then offsets stored
// raw and mask as 2*sigmoid. XCD-contiguous strip swizzle.
// ---------------------------------------------------------------------------
__global__ __launch_bounds__(256, 4) void k_offmask(const float* __restrict__ xcat,
                                                    const float* __restrict__ ow,
                                                    const float* __restrict__ ob,
                                                    const float* __restrict__ mw,
                                                    const float* __restrict__ mb,
                                                    float* __restrict__ offb,
                                                    float* __restrict__ maskb) {
    __shared__ float red[4 * 27 * 64];  // 27648 B
    int lane = threadIdx.x & 63;
    int wid = __builtin_amdgcn_readfirstlane((int)(threadIdx.x >> 6));
    int blk = blockIdx.x;
    int sg = (blk & 7) * 128 + (blk >> 3);  // XCD-contiguous strip id
    int b = sg >> 8;
    int hwbase = (sg & 255) * 64;
    int hw = hwbase + lane, y = hw >> 7, x = hw & (W - 1);
    int c0 = (CIN * wid) >> 2, c1 = (CIN * (wid + 1)) >> 2;

    float acc[27];
#pragma unroll
    for (int i = 0; i < 27; i++) acc[i] = 0.f;
    const float* xb = xcat + (size_t)b * CIN * HW;
    for (int c = c0; c < c1; c++) {
        float p[9];
        load_patch(xb + c * HW, y, x, p);
#pragma unroll
        for (int oc = 0; oc < 18; oc++) {
            const float* w = ow + (size_t)oc * (CIN * 9) + c * 9;
#pragma unroll
            for (int tt = 0; tt < 9; tt++) acc[oc] += p[tt] * w[tt];
        }
#pragma unroll
        for (int oc = 0; oc < 9; oc++) {
            const float* w = mw + (size_t)oc * (CIN * 9) + c * 9;
#pragma unroll
            for (int tt = 0; tt < 9; tt++) acc[18 + oc] += p[tt] * w[tt];
        }
    }
#pragma unroll
    for (int j = 0; j < 27; j++) red[(wid * 27 + j) * 64 + lane] = acc[j];
    __syncthreads();
    for (int idx = threadIdx.x; idx < 27 * 64; idx += 256) {
        int j = idx >> 6, px = idx & 63;
        float s = red[j * 64 + px] + red[(27 + j) * 64 + px]
                + red[(54 + j) * 64 + px] + red[(81 + j) * 64 + px];
        if (j < 18) {
            offb[(b * 18 + j) * HW + hwbase + px] = s + ob[j];
        } else {
            int mj = j - 18;
            maskb[(b * 9 + mj) * HW + hwbase + px] = 2.f * fast_sigmoid(s + mb[mj]);
        }
    }
}

// ---------------------------------------------------------------------------
// Deformable conv as fused implicit GEMM, barrier-free / LDS-free.
// Block = 256 thr = 4 waves = 64 px strip; wave nt owns 16 pixels (N-tile).
// Per tap: each lane computes bilinear coefs for ITS pixel (n=lane&15,
// 4x q-redundant), then per ks builds its B-fragment in registers (8 channel
// gathers, k = q*8+j) and runs 4 MFMAs vs prepacked A-frags. Each (px,tap,c)
// value computed exactly once per block; gathers/packs/MFMAs pipeline freely
// (no barriers). 16 acc VGPRs. XCD-contiguous strip swizzle.
// ---------------------------------------------------------------------------
__global__ __launch_bounds__(256) void k_deform(const float* __restrict__ xcat,
                                                const float* __restrict__ offb,
                                                const float* __restrict__ maskb,
                                                const unsigned short* __restrict__ apk,
                                                const float* __restrict__ bias,
                                                float* __restrict__ xout) {
    int lane = threadIdx.x & 63;
    int nt = __builtin_amdgcn_readfirstlane((int)(threadIdx.x >> 6));
    int blk = blockIdx.x;
    int sg = (blk & 7) * 128 + (blk >> 3);  // XCD-contiguous strip id
    int b = sg >> 8;
    int hwbase = (sg & 255) * 64;
    int n = lane & 15, q = lane >> 4;
    int hw = hwbase + nt * 16 + n;
    int y = hw >> 7, x = hw & (W - 1);

    f32x4 acc[4];
#pragma unroll
    for (int mt = 0; mt < 4; mt++) { f32x4 z = {0.f, 0.f, 0.f, 0.f}; acc[mt] = z; }

    const float* xb = xcat + (size_t)b * CIN * HW;
#pragma unroll 1
    for (int tap = 0; tap < K2; tap++) {
        // per-lane bilinear setup for this (pixel, tap)
        int ky = tap / 3, kx = tap - ky * 3;
        float offy = offb[(b * 18 + 2 * tap) * HW + hw];
        float offx = offb[(b * 18 + 2 * tap + 1) * HW + hw];
        float m = maskb[(b * 9 + tap) * HW + hw];
        float py = (float)(y + ky - 1) + offy;
        float px_ = (float)(x + kx - 1) + offx;
        float fy = floorf(py), fx = floorf(px_);
        float wy = py - fy, wx = px_ - fx;
        int y0 = (int)fy, x0 = (int)fx;
        int y1 = y0 + 1, x1 = x0 + 1;
        float vy0 = (y0 >= 0 && y0 <= H - 1) ? 1.f : 0.f;
        float vy1 = (y1 >= 0 && y1 <= H - 1) ? 1.f : 0.f;
        float vx0 = (x0 >= 0 && x0 <= W - 1) ? 1.f : 0.f;
        float vx1 = (x1 >= 0 && x1 <= W - 1) ? 1.f : 0.f;
        int yc0 = min(max(y0, 0), H - 1), yc1 = min(max(y1, 0), H - 1);
        int xc0 = min(max(x0, 0), W - 1), xc1 = min(max(x1, 0), W - 1);
        float a00 = (1.f - wy) * (1.f - wx) * m * vy0 * vx0;
        float a01 = (1.f - wy) * wx * m * vy0 * vx1;
        float a10 = wy * (1.f - wx) * m * vy1 * vx0;
        float a11 = wy * wx * m * vy1 * vx1;
        int j00 = yc0 * W + xc0, j01 = yc0 * W + xc1;
        int j10 = yc1 * W + xc0, j11 = yc1 * W + xc1;

        const unsigned short* ab = apk + (size_t)(tap * 12) * 512 + lane * 8;
#pragma unroll
        for (int ks = 0; ks < 3; ks++) {
            // B-fragment in registers: 8 channels of this lane's pixel
            bf16x8 bf;
#pragma unroll
            for (int j = 0; j < 8; j++) {
                int c = ks * 32 + q * 8 + j;
                float v = 0.f;
                if (c < CIN) {
                    const float* xc = xb + c * HW;
                    v = a00 * xc[j00] + a01 * xc[j01] + a10 * xc[j10] + a11 * xc[j11];
                }
                bf[j] = (short)f2bf(v);
            }
#pragma unroll
            for (int mt = 0; mt < 4; mt++) {
                bf16x8 af = *(const bf16x8*)(ab + (size_t)(ks * 4 + mt) * 512);
                acc[mt] = __builtin_amdgcn_mfma_f32_16x16x32_bf16(af, bf, acc[mt], 0, 0, 0);
            }
        }
    }

    // epilogue: D[row=q*4+r][col=n]
    float* xo = xout + (size_t)b * CIN * HW + hwbase + nt * 16 + n;
#pragma unroll
    for (int mt = 0; mt < 4; mt++) {
#pragma unroll
        for (int r = 0; r < 4; r++) {
            int o = mt * 16 + q * 4 + r;
            xo[(size_t)o * HW] = acc[mt][r] + bias[o];
        }
    }
}

// final 3-channel conv over 67-channel concat; blockIdx.y = output channel
__global__ __launch_bounds__(256) void k_conv3(const float* __restrict__ xcat,
                                               const float* __restrict__ cw,
                                               const float* __restrict__ cb,
                                               float* __restrict__ y3) {
    int t = blockIdx.x * blockDim.x + threadIdx.x;
    int b = t >> 14, hw = t & (HW - 1), y = hw >> 7, x = hw & (W - 1);
    int oc = blockIdx.y;
    float acc = cb[oc];
    const float* xb = xcat + (size_t)b * CIN * HW;
    const float* wb = cw + (size_t)oc * (CIN * 9);
    for (int c = 0; c < CIN; c++) {
        float p[9];
        load_patch(xb + c * HW, y, x, p);
        const float* w = wb + c * 9;
#pragma unroll
        for (int tt = 0; tt < 9; tt++) acc += p[tt] * w[tt];
    }
    y3[(b * NC + oc) * HW + hw] = acc;
}

// global average pool: one block per (b,c)
__global__ __launch_bounds__(256) void k_pool(const float* __restrict__ y3,
                                              float* __restrict__ pooled) {
    int bc = blockIdx.x;  // 0..11
    const float* p = y3 + (size_t)bc * HW;
    float s = 0.f;
    for (int i = threadIdx.x; i < HW; i += 256) s += p[i];
    __shared__ float red[256];
    red[threadIdx.x] = s;
    __syncthreads();
    for (int off = 128; off > 0; off >>= 1) {
        if (threadIdx.x < off) red[threadIdx.x] += red[threadIdx.x + off];
        __syncthreads();
    }
    if (threadIdx.x == 0) pooled[bc] = red[0] / (float)HW;
}

// tiny per-branch channel MLP -> ch[b,s,c,k]
__global__ void k_ch(const float* __restrict__ pooled, const float* __restrict__ w1,
                     const float* __restrict__ b1, const float* __restrict__ w2,
                     const float* __restrict__ b2, float* __restrict__ chbuf) {
    int t = threadIdx.x;
    if (t >= B * S2) return;
    int b = t >> 4, s = t & 15;
    float h1[MID];
#pragma unroll
    for (int m = 0; m < MID; m++) {
        float a = b1[s * MID + m];
#pragma unroll
        for (int c = 0; c < NC; c++) a += pooled[b * NC + c] * w1[(s * MID + m) * NC + c];
        h1[m] = fmaxf(a, 0.f);
    }
    for (int kk = 0; kk < NC * K2; kk++) {
        float a = b2[s * (NC * K2) + kk];
#pragma unroll
        for (int m = 0; m < MID; m++) a += h1[m] * w2[(s * (NC * K2) + kk) * MID + m];
        chbuf[(b * S2 + s) * (NC * K2) + kk] = a;
    }
}

// ---------------------------------------------------------------------------
// Fused DDF upsample: spatial-filter conv + dynamic combine + pixel_shuffle
// + clip. blockIdx.y selects 4 of the 16 branches; that quarter of sp_w/sp_b
// and ch staged in LDS (block is single-batch).
// ---------------------------------------------------------------------------
__global__ __launch_bounds__(256) void k_ddf(const float* __restrict__ y3,
                                             const float* __restrict__ spw,
                                             const float* __restrict__ spb,
                                             const float* __restrict__ chbuf,
                                             float* __restrict__ out) {
    __shared__ float s_spw[4 * K2 * NC * 9];  // 972
    __shared__ float s_spb[4 * K2];           // 36
    __shared__ float s_ch[4 * NC * K2];       // 108
    int t = blockIdx.x * blockDim.x + threadIdx.x;
    int b = t >> 14, hw = t & (HW - 1), y = hw >> 7, x = hw & (W - 1);
    int s0 = blockIdx.y * 4;
    for (int i = threadIdx.x; i < 4 * K2 * NC * 9; i += 256) s_spw[i] = spw[s0 * K2 * NC * 9 + i];
    if (threadIdx.x < 4 * K2) s_spb[threadIdx.x] = spb[s0 * K2 + threadIdx.x];
    if (threadIdx.x < 4 * NC * K2) s_ch[threadIdx.x] = chbuf[b * (S2 * NC * K2) + s0 * NC * K2 + threadIdx.x];
    __syncthreads();
    float p[NC][9];
#pragma unroll
    for (int c = 0; c < NC; c++) load_patch(y3 + (b * NC + c) * HW, y, x, p[c]);
#pragma unroll
    for (int si = 0; si < 4; si++) {
        int s = s0 + si;
        float spv[K2];
#pragma unroll
        for (int k = 0; k < K2; k++) {
            float a = s_spb[si * K2 + k];
            const float* w = s_spw + (si * K2 + k) * (NC * 9);
#pragma unroll
            for (int c = 0; c < NC; c++)
#pragma unroll
                for (int tt = 0; tt < 9; tt++) a += p[c][tt] * w[c * 9 + tt];
            spv[k] = a;
        }
        int sy = s >> 2, sx = s & 3;
#pragma unroll
        for (int c = 0; c < NC; c++) {
            float a = 0.f;
            const float* chp = s_ch + (si * NC + c) * K2;
#pragma unroll
            for (int k = 0; k < K2; k++) a += p[c][k] * (chp[k] + spv[k]);
            a = fminf(fmaxf(a, 0.f), 255.f);
            out[((size_t)(b * NC + c) * OUT_HW + (y * SCALE + sy)) * OUT_HW + (x * SCALE + sx)] = a;
        }
    }
}

extern "C" void kernel_launch(void* const* d_in, const int* in_sizes, int n_in,
                              void* d_out, int out_size, void* d_ws, size_t ws_size,
                              hipStream_t stream) {
    const float* X = (const float*)d_in[0];
    const float* lstm_w = (const float*)d_in[1];
    const float* lstm_b = (const float*)d_in[2];
    const float* ow[3] = {(const float*)d_in[3], (const float*)d_in[9], (const float*)d_in[15]};
    const float* ob[3] = {(const float*)d_in[4], (const float*)d_in[10], (const float*)d_in[16]};
    const float* mw[3] = {(const float*)d_in[5], (const float*)d_in[11], (const float*)d_in[17]};
    const float* mb[3] = {(const float*)d_in[6], (const float*)d_in[12], (const float*)d_in[18]};
    const float* dw[3] = {(const float*)d_in[7], (const float*)d_in[13], (const float*)d_in[19]};
    const float* db[3] = {(const float*)d_in[8], (const float*)d_in[14], (const float*)d_in[20]};
    const float* conv_w = (const float*)d_in[21];
    const float* conv_b = (const float*)d_in[22];
    const float* sp_w = (const float*)d_in[23];
    const float* sp_b = (const float*)d_in[24];
    const float* ch_w1 = (const float*)d_in[25];
    const float* ch_b1 = (const float*)d_in[26];
    const float* ch_w2 = (const float*)d_in[27];
    const float* ch_b2 = (const float*)d_in[28];

    float* out = (float*)d_out;
    const size_t OUT_IMG = (size_t)B * NC * OUT_HW * OUT_HW;  // 3145728
    const size_t HIDSZ = (size_t)B * NK * HW;                 // 4194304
    float* hid_out = out + OUT_IMG;
    float* cell_out = out + OUT_IMG + HIDSZ;

    float* ws = (float*)d_ws;
    const size_t XCAT = (size_t)B * CIN * HW;  // 4390912
    float* xcatA = ws;            ws += XCAT;
    float* xcatB = ws;            ws += XCAT;
    float* offb = ws;             ws += (size_t)B * 18 * HW;
    float* maskb = ws;            ws += (size_t)B * 9 * HW;
    unsigned short* apk[3];
    for (int i = 0; i < 3; i++) { apk[i] = (unsigned short*)ws; ws += 108 * 512 / 2; }
    float* y3 = ws;               ws += (size_t)B * NC * HW;
    float* pooled = ws;           ws += 16;
    float* chbuf = ws;            ws += (size_t)B * S2 * NC * K2;

    dim3 blk(256);
    dim3 g1(B * HW / 256);        // 256 blocks
    dim3 g4(B * HW / 256, 4);
    dim3 g3(B * HW / 256, 3);
    dim3 gd(B * HW / 64);         // 1024 strips

    k_lstm<<<g4, blk, 0, stream>>>(X, lstm_w, lstm_b, xcatA, hid_out, cell_out);
    k_copy_lr<<<g1, blk, 0, stream>>>(X, xcatA, xcatB);
    for (int i = 0; i < 3; i++)
        k_prepA<<<dim3(108), dim3(512), 0, stream>>>(dw[i], apk[i]);

    // layer 1: xcatA -> xcatB
    k_offmask<<<gd, blk, 0, stream>>>(xcatA, ow[0], ob[0], mw[0], mb[0], offb, maskb);
    k_deform<<<gd, blk, 0, stream>>>(xcatA, offb, maskb, apk[0], db[0], xcatB);
    // layer 2: xcatB -> xcatA
    k_offmask<<<gd, blk, 0, stream>>>(xcatB, ow[1], ob[1], mw[1], mb[1], offb, maskb);
    k_deform<<<gd, blk, 0, stream>>>(xcatB, offb, maskb, apk[1], db[1], xcatA);
    // layer 3: xcatA -> xcatB
    k_offmask<<<gd, blk, 0, stream>>>(xcatA, ow[2], ob[2], mw[2], mb[2], offb, maskb);
    k_deform<<<gd, blk, 0, stream>>>(xcatA, offb, maskb, apk[2], db[2], xcatB);

    k_conv3<<<g3, blk, 0, stream>>>(xcatB, conv_w, conv_b, y3);
    k_pool<<<dim3(B * NC), blk, 0, stream>>>(y3, pooled);
    k_ch<<<dim3(1), dim3(64), 0, stream>>>(pooled, ch_w1, ch_b1, ch_w2, ch_b2, chbuf);
    k_ddf<<<g4, blk, 0, stream>>>(y3, sp_w, sp_b, chbuf, out);
}

// Round 10
// 622.071 us; speedup vs baseline: 1.1517x; 1.1046x over previous
//
#include <hip/hip_runtime.h>
#include <hip/hip_bf16.h>
#include <math.h>

// Problem constants
#define NC 3
#define NK 64
#define KK 3
#define K2 9
#define PAD 1
#define SCALE 4
#define S2 16
#define MID 4
#define B 4
#define H 128
#define W 128
#define HW (H*W)          // 16384
#define CIN 67            // NK + NC
#define OUT_HW (H*SCALE)  // 512

typedef short bf16x8 __attribute__((ext_vector_type(8)));
typedef float f32x4 __attribute__((ext_vector_type(4)));

__device__ __forceinline__ float fast_sigmoid(float v) { return 1.f / (1.f + __expf(-v)); }
__device__ __forceinline__ float fast_tanh(float v) { return 2.f / (1.f + __expf(-2.f * v)) - 1.f; }

// fp32 -> bf16 round-to-nearest-even
__device__ __forceinline__ unsigned short f2bf(float f) {
    unsigned int u = __float_as_uint(f);
    unsigned int r = (u + 0x7FFFu + ((u >> 16) & 1u)) >> 16;
    return (unsigned short)r;
}

// load a zero-padded 3x3 patch of one channel plane (HxW) at (y,x)
__device__ __forceinline__ void load_patch(const float* __restrict__ xc, int y, int x, float* p) {
#pragma unroll
    for (int dy = -1; dy <= 1; dy++) {
#pragma unroll
        for (int dx = -1; dx <= 1; dx++) {
            int yy = y + dy, xx = x + dx;
            float v = (yy >= 0 && yy < H && xx >= 0 && xx < W) ? xc[yy * W + xx] : 0.f;
            p[(dy + 1) * 3 + (dx + 1)] = v;
        }
    }
}

// ---------------------------------------------------------------------------
// ConvLSTM with h=0,c=0: only first NC input channels of lstm_w matter;
// f-gate irrelevant (c_prev=0). blockIdx.y selects a 16-channel gate group.
// ---------------------------------------------------------------------------
__global__ __launch_bounds__(256) void k_lstm(const float* __restrict__ X,
                                              const float* __restrict__ lw,
                                              const float* __restrict__ lb,
                                              float* __restrict__ xcatA,
                                              float* __restrict__ hid_out,
                                              float* __restrict__ cell_out) {
    int t = blockIdx.x * blockDim.x + threadIdx.x;
    int b = t >> 14, hw = t & (HW - 1), y = hw >> 7, x = hw & (W - 1);
    int nk0 = blockIdx.y * 16;
    float p[NC][9];
#pragma unroll
    for (int c = 0; c < NC; c++) load_patch(X + (b * NC + c) * HW, y, x, p[c]);
    float* xc = xcatA + (size_t)b * CIN * HW;
    for (int i = 0; i < 16; i++) {
        int nk = nk0 + i;
        float gi = lb[nk], go = lb[2 * NK + nk], gg = lb[3 * NK + nk];
#pragma unroll
        for (int c = 0; c < NC; c++) {
            const float* wi = lw + (size_t)(nk) * (CIN * 9) + c * 9;
            const float* wo = lw + (size_t)(2 * NK + nk) * (CIN * 9) + c * 9;
            const float* wg = lw + (size_t)(3 * NK + nk) * (CIN * 9) + c * 9;
#pragma unroll
            for (int tt = 0; tt < 9; tt++) {
                gi += p[c][tt] * wi[tt];
                go += p[c][tt] * wo[tt];
                gg += p[c][tt] * wg[tt];
            }
        }
        float cv = fast_sigmoid(gi) * fast_tanh(gg);
        float hv = fast_sigmoid(go) * fast_tanh(cv);
        xc[nk * HW + hw] = hv;
        hid_out[(b * NK + nk) * HW + hw] = hv;
        cell_out[(b * NK + nk) * HW + hw] = cv;
    }
}

// copy lr (X) into channels 64..66 of both xcat buffers
__global__ __launch_bounds__(256) void k_copy_lr(const float* __restrict__ X,
                                                 float* __restrict__ xcatA,
                                                 float* __restrict__ xcatB) {
    int t = blockIdx.x * blockDim.x + threadIdx.x;
    int b = t >> 14, hw = t & (HW - 1);
#pragma unroll
    for (int c = 0; c < NC; c++) {
        float v = X[(b * NC + c) * HW + hw];
        xcatA[(size_t)b * CIN * HW + (NK + c) * HW + hw] = v;
        xcatB[(size_t)b * CIN * HW + (NK + c) * HW + hw] = v;
    }
}

// ---------------------------------------------------------------------------
// Prepack deform weights dw[o<64][c<67][k<9] into MFMA A-fragment order, bf16:
// frag g = (tap*3+ks)*4+mt: apk[g*512 + lane*8 + j] = A[m][kc] with
// m = mt*16+(lane&15), kc = ks*32+(lane>>4)*8+j (per-tap channel; 0 if >=67).
// grid 108 blocks x 512 threads.
// ---------------------------------------------------------------------------
__global__ void k_prepA(const float* __restrict__ w, unsigned short* __restrict__ apk) {
    int g = blockIdx.x;            // (tap*3+ks)*4+mt
    int tid = threadIdx.x;         // 0..511
    int lane = tid >> 3, j = tid & 7;
    int mt = g & 3, r = g >> 2;    // r = tap*3+ks
    int ks = r % 3, tap = r / 3;
    int o = mt * 16 + (lane & 15);
    int c = ks * 32 + ((lane >> 4) << 3) + j;
    float val = (c < CIN) ? w[(size_t)o * (CIN * 9) + c * 9 + tap] : 0.f;
    apk[(size_t)g * 512 + tid] = f2bf(val);
}

// ---------------------------------------------------------------------------
// Prepack offset(18)+mask(9) conv weights into M=32 A-fragments, bf16:
// frag g = (tap*3+kss)*2+mt: o = mt*16+(lane&15) (o<18 -> ow row, 18..26 ->
// mw row o-18, else 0), c = kss*32+(lane>>4)*8+j (0 if >=67).
// grid 54 x 512.
// ---------------------------------------------------------------------------
__global__ void k_prepOM(const float* __restrict__ ow, const float* __restrict__ mw,
                         unsigned short* __restrict__ apk) {
    int g = blockIdx.x;            // (tap*3+kss)*2+mt
    int tid = threadIdx.x;         // 0..511
    int lane = tid >> 3, j = tid & 7;
    int mt = g & 1, r = g >> 1;    // r = tap*3+kss
    int kss = r % 3, tap = r / 3;
    int o = mt * 16 + (lane & 15);
    int c = kss * 32 + ((lane >> 4) << 3) + j;
    float val = 0.f;
    if (c < CIN) {
        if (o < 18) val = ow[(size_t)o * (CIN * 9) + c * 9 + tap];
        else if (o < 27) val = mw[(size_t)(o - 18) * (CIN * 9) + c * 9 + tap];
    }
    apk[(size_t)g * 512 + tid] = f2bf(val);
}

// ---------------------------------------------------------------------------
// Offset + mask convs as MFMA implicit GEMM. Block = 256 thr = 4 waves =
// 64 px strip; wave nt owns 16 px (N-tile). Per tap: regular (zero-padded)
// patch sample per lane; per kss a register B-frag (8 channel loads) and
// 2 MFMAs vs prepacked A (M=32 covers 27 outputs). Epilogue: bias + raw
// offsets / 2*sigmoid mask. Barrier-free, LDS-free. XCD strip swizzle.
// ---------------------------------------------------------------------------
__global__ __launch_bounds__(256) void k_offmask(const float* __restrict__ xcat,
                                                 const unsigned short* __restrict__ apk,
                                                 const float* __restrict__ ob,
                                                 const float* __restrict__ mb,
                                                 float* __restrict__ offb,
                                                 float* __restrict__ maskb) {
    int tid = threadIdx.x;
    int lane = tid & 63;
    int nt = __builtin_amdgcn_readfirstlane(tid >> 6);
    int blk = blockIdx.x;
    int sg = (blk & 7) * 128 + (blk >> 3);  // XCD-contiguous strip id
    int b = sg >> 8;
    int hwbase = (sg & 255) * 64;
    int n = lane & 15, q = lane >> 4;
    int hw = hwbase + nt * 16 + n;
    int y = hw >> 7, x = hw & (W - 1);

    f32x4 acc[2];
#pragma unroll
    for (int mt = 0; mt < 2; mt++) { f32x4 z = {0.f, 0.f, 0.f, 0.f}; acc[mt] = z; }

    const float* xb = xcat + (size_t)b * CIN * HW;
#pragma unroll 1
    for (int tap = 0; tap < K2; tap++) {
        int ky = tap / 3, kx = tap - ky * 3;
        int yy = y + ky - 1, xx = x + kx - 1;
        float valid = (yy >= 0 && yy < H && xx >= 0 && xx < W) ? 1.f : 0.f;
        int ii = min(max(yy, 0), H - 1) * W + min(max(xx, 0), W - 1);
        const unsigned short* ab = apk + (size_t)(tap * 6) * 512 + lane * 8;
#pragma unroll
        for (int kss = 0; kss < 3; kss++) {
            bf16x8 bf;
#pragma unroll
            for (int j = 0; j < 8; j++) {
                int c = kss * 32 + q * 8 + j;
                float v = 0.f;
                if (c < CIN) v = xb[(size_t)c * HW + ii] * valid;
                bf[j] = (short)f2bf(v);
            }
#pragma unroll
            for (int mt = 0; mt < 2; mt++) {
                bf16x8 af = *(const bf16x8*)(ab + (size_t)(kss * 2 + mt) * 512);
                acc[mt] = __builtin_amdgcn_mfma_f32_16x16x32_bf16(af, bf, acc[mt], 0, 0, 0);
            }
        }
    }

    // epilogue: D[row=q*4+r][col=n]; rows 0..17 offsets, 18..26 mask
#pragma unroll
    for (int mt = 0; mt < 2; mt++) {
#pragma unroll
        for (int r = 0; r < 4; r++) {
            int o = mt * 16 + q * 4 + r;
            float v = acc[mt][r];
            if (o < 18) {
                offb[(size_t)(b * 18 + o) * HW + hw] = v + ob[o];
            } else if (o < 27) {
                maskb[(size_t)(b * 9 + (o - 18)) * HW + hw] = 2.f * fast_sigmoid(v + mb[o - 18]);
            }
        }
    }
}

// ---------------------------------------------------------------------------
// Deformable conv as fused implicit GEMM, split-K x2. Block = 256 thr =
// 32 px strip; wave = (N-tile nt2 in {0,1}) x (K-half kh: taps 0-4 / 5-8).
// 8192 waves total -> 32 waves/CU (vs 16 unsplit) for latency hiding.
// Per tap: per-lane bilinear coefs for its pixel, register B-frags (8 channel
// gathers each), 4 MFMAs vs prepacked A. kh=1 partials through LDS (17-pad,
// <=2-way conflicts = free), single barrier. XCD strip swizzle.
// ---------------------------------------------------------------------------
__global__ __launch_bounds__(256) void k_deform(const float* __restrict__ xcat,
                                                const float* __restrict__ offb,
                                                const float* __restrict__ maskb,
                                                const unsigned short* __restrict__ apk,
                                                const float* __restrict__ bias,
                                                float* __restrict__ xout) {
    __shared__ float red[2 * 64 * 17];  // 8704 B
    int tid = threadIdx.x;
    int lane = tid & 63;
    int wid = __builtin_amdgcn_readfirstlane(tid >> 6);
    int nt2 = wid & 1, kh = wid >> 1;
    int blk = blockIdx.x;                    // 0..2047
    int sg = (blk & 7) * 256 + (blk >> 3);   // XCD-contiguous strip id
    int b = sg >> 9;
    int hwbase = (sg & 511) * 32;
    int n = lane & 15, q = lane >> 4;
    int hw = hwbase + nt2 * 16 + n;
    int y = hw >> 7, x = hw & (W - 1);

    f32x4 acc[4];
#pragma unroll
    for (int mt = 0; mt < 4; mt++) { f32x4 z = {0.f, 0.f, 0.f, 0.f}; acc[mt] = z; }

    const float* xb = xcat + (size_t)b * CIN * HW;
    int t0 = kh ? 5 : 0, t1 = kh ? 9 : 5;
#pragma unroll 1
    for (int tap = t0; tap < t1; tap++) {
        // per-lane bilinear setup for this (pixel, tap)
        int ky = tap / 3, kx = tap - ky * 3;
        float offy = offb[(b * 18 + 2 * tap) * HW + hw];
        float offx = offb[(b * 18 + 2 * tap + 1) * HW + hw];
        float m = maskb[(b * 9 + tap) * HW + hw];
        float py = (float)(y + ky - 1) + offy;
        float px_ = (float)(x + kx - 1) + offx;
        float fy = floorf(py), fx = floorf(px_);
        float wy = py - fy, wx = px_ - fx;
        int y0 = (int)fy, x0 = (int)fx;
        int y1 = y0 + 1, x1 = x0 + 1;
        float vy0 = (y0 >= 0 && y0 <= H - 1) ? 1.f : 0.f;
        float vy1 = (y1 >= 0 && y1 <= H - 1) ? 1.f : 0.f;
        float vx0 = (x0 >= 0 && x0 <= W - 1) ? 1.f : 0.f;
        float vx1 = (x1 >= 0 && x1 <= W - 1) ? 1.f : 0.f;
        int yc0 = min(max(y0, 0), H - 1), yc1 = min(max(y1, 0), H - 1);
        int xc0 = min(max(x0, 0), W - 1), xc1 = min(max(x1, 0), W - 1);
        float a00 = (1.f - wy) * (1.f - wx) * m * vy0 * vx0;
        float a01 = (1.f - wy) * wx * m * vy0 * vx1;
        float a10 = wy * (1.f - wx) * m * vy1 * vx0;
        float a11 = wy * wx * m * vy1 * vx1;
        int j00 = yc0 * W + xc0, j01 = yc0 * W + xc1;
        int j10 = yc1 * W + xc0, j11 = yc1 * W + xc1;

        const unsigned short* ab = apk + (size_t)(tap * 12) * 512 + lane * 8;
#pragma unroll
        for (int ks = 0; ks < 3; ks++) {
            bf16x8 bf;
#pragma unroll
            for (int j = 0; j < 8; j++) {
                int c = ks * 32 + q * 8 + j;
                float v = 0.f;
                if (c < CIN) {
                    const float* xc = xb + c * HW;
                    v = a00 * xc[j00] + a01 * xc[j01] + a10 * xc[j10] + a11 * xc[j11];
                }
                bf[j] = (short)f2bf(v);
            }
#pragma unroll
            for (int mt = 0; mt < 4; mt++) {
                bf16x8 af = *(const bf16x8*)(ab + (size_t)(ks * 4 + mt) * 512);
                acc[mt] = __builtin_amdgcn_mfma_f32_16x16x32_bf16(af, bf, acc[mt], 0, 0, 0);
            }
        }
    }

    // split-K reduction: kh=1 waves stage partials, kh=0 waves add + store
    if (kh) {
#pragma unroll
        for (int mt = 0; mt < 4; mt++) {
#pragma unroll
            for (int r = 0; r < 4; r++) {
                int o = mt * 16 + q * 4 + r;
                red[(nt2 * 64 + o) * 17 + n] = acc[mt][r];
            }
        }
    }
    __syncthreads();
    if (!kh) {
        float* xo = xout + (size_t)b * CIN * HW + hwbase + nt2 * 16 + n;
#pragma unroll
        for (int mt = 0; mt < 4; mt++) {
#pragma unroll
            for (int r = 0; r < 4; r++) {
                int o = mt * 16 + q * 4 + r;
                xo[(size_t)o * HW] = acc[mt][r] + red[(nt2 * 64 + o) * 17 + n] + bias[o];
            }
        }
    }
}

// final 3-channel conv over 67-channel concat; blockIdx.y = output channel
__global__ __launch_bounds__(256) void k_conv3(const float* __restrict__ xcat,
                                               const float* __restrict__ cw,
                                               const float* __restrict__ cb,
                                               float* __restrict__ y3) {
    int t = blockIdx.x * blockDim.x + threadIdx.x;
    int b = t >> 14, hw = t & (HW - 1), y = hw >> 7, x = hw & (W - 1);
    int oc = blockIdx.y;
    float acc = cb[oc];
    const float* xb = xcat + (size_t)b * CIN * HW;
    const float* wb = cw + (size_t)oc * (CIN * 9);
    for (int c = 0; c < CIN; c++) {
        float p[9];
        load_patch(xb + c * HW, y, x, p);
        const float* w = wb + c * 9;
#pragma unroll
        for (int tt = 0; tt < 9; tt++) acc += p[tt] * w[tt];
    }
    y3[(b * NC + oc) * HW + hw] = acc;
}

// global average pool: one block per (b,c)
__global__ __launch_bounds__(256) void k_pool(const float* __restrict__ y3,
                                              float* __restrict__ pooled) {
    int bc = blockIdx.x;  // 0..11
    const float* p = y3 + (size_t)bc * HW;
    float s = 0.f;
    for (int i = threadIdx.x; i < HW; i += 256) s += p[i];
    __shared__ float red[256];
    red[threadIdx.x] = s;
    __syncthreads();
    for (int off = 128; off > 0; off >>= 1) {
        if (threadIdx.x < off) red[threadIdx.x] += red[threadIdx.x + off];
        __syncthreads();
    }
    if (threadIdx.x == 0) pooled[bc] = red[0] / (float)HW;
}

// tiny per-branch channel MLP -> ch[b,s,c,k]
__global__ void k_ch(const float* __restrict__ pooled, const float* __restrict__ w1,
                     const float* __restrict__ b1, const float* __restrict__ w2,
                     const float* __restrict__ b2, float* __restrict__ chbuf) {
    int t = threadIdx.x;
    if (t >= B * S2) return;
    int b = t >> 4, s = t & 15;
    float h1[MID];
#pragma unroll
    for (int m = 0; m < MID; m++) {
        float a = b1[s * MID + m];
#pragma unroll
        for (int c = 0; c < NC; c++) a += pooled[b * NC + c] * w1[(s * MID + m) * NC + c];
        h1[m] = fmaxf(a, 0.f);
    }
    for (int kk = 0; kk < NC * K2; kk++) {
        float a = b2[s * (NC * K2) + kk];
#pragma unroll
        for (int m = 0; m < MID; m++) a += h1[m] * w2[(s * (NC * K2) + kk) * MID + m];
        chbuf[(b * S2 + s) * (NC * K2) + kk] = a;
    }
}

// ---------------------------------------------------------------------------
// Fused DDF upsample: spatial-filter conv + dynamic combine + pixel_shuffle
// + clip. blockIdx.y selects 4 of the 16 branches; that quarter of sp_w/sp_b
// and ch staged in LDS (block is single-batch).
// ---------------------------------------------------------------------------
__global__ __launch_bounds__(256) void k_ddf(const float* __restrict__ y3,
                                             const float* __restrict__ spw,
                                             const float* __restrict__ spb,
                                             const float* __restrict__ chbuf,
                                             float* __restrict__ out) {
    __shared__ float s_spw[4 * K2 * NC * 9];  // 972
    __shared__ float s_spb[4 * K2];           // 36
    __shared__ float s_ch[4 * NC * K2];       // 108
    int t = blockIdx.x * blockDim.x + threadIdx.x;
    int b = t >> 14, hw = t & (HW - 1), y = hw >> 7, x = hw & (W - 1);
    int s0 = blockIdx.y * 4;
    for (int i = threadIdx.x; i < 4 * K2 * NC * 9; i += 256) s_spw[i] = spw[s0 * K2 * NC * 9 + i];
    if (threadIdx.x < 4 * K2) s_spb[threadIdx.x] = spb[s0 * K2 + threadIdx.x];
    if (threadIdx.x < 4 * NC * K2) s_ch[threadIdx.x] = chbuf[b * (S2 * NC * K2) + s0 * NC * K2 + threadIdx.x];
    __syncthreads();
    float p[NC][9];
#pragma unroll
    for (int c = 0; c < NC; c++) load_patch(y3 + (b * NC + c) * HW, y, x, p[c]);
#pragma unroll
    for (int si = 0; si < 4; si++) {
        int s = s0 + si;
        float spv[K2];
#pragma unroll
        for (int k = 0; k < K2; k++) {
            float a = s_spb[si * K2 + k];
            const float* w = s_spw + (si * K2 + k) * (NC * 9);
#pragma unroll
            for (int c = 0; c < NC; c++)
#pragma unroll
                for (int tt = 0; tt < 9; tt++) a += p[c][tt] * w[c * 9 + tt];
            spv[k] = a;
        }
        int sy = s >> 2, sx = s & 3;
#pragma unroll
        for (int c = 0; c < NC; c++) {
            float a = 0.f;
            const float* chp = s_ch + (si * NC + c) * K2;
#pragma unroll
            for (int k = 0; k < K2; k++) a += p[c][k] * (chp[k] + spv[k]);
            a = fminf(fmaxf(a, 0.f), 255.f);
            out[((size_t)(b * NC + c) * OUT_HW + (y * SCALE + sy)) * OUT_HW + (x * SCALE + sx)] = a;
        }
    }
}

extern "C" void kernel_launch(void* const* d_in, const int* in_sizes, int n_in,
                              void* d_out, int out_size, void* d_ws, size_t ws_size,
                              hipStream_t stream) {
    const float* X = (const float*)d_in[0];
    const float* lstm_w = (const float*)d_in[1];
    const float* lstm_b = (const float*)d_in[2];
    const float* ow[3] = {(const float*)d_in[3], (const float*)d_in[9], (const float*)d_in[15]};
    const float* ob[3] = {(const float*)d_in[4], (const float*)d_in[10], (const float*)d_in[16]};
    const float* mw[3] = {(const float*)d_in[5], (const float*)d_in[11], (const float*)d_in[17]};
    const float* mb[3] = {(const float*)d_in[6], (const float*)d_in[12], (const float*)d_in[18]};
    const float* dw[3] = {(const float*)d_in[7], (const float*)d_in[13], (const float*)d_in[19]};
    const float* db[3] = {(const float*)d_in[8], (const float*)d_in[14], (const float*)d_in[20]};
    const float* conv_w = (const float*)d_in[21];
    const float* conv_b = (const float*)d_in[22];
    const float* sp_w = (const float*)d_in[23];
    const float* sp_b = (const float*)d_in[24];
    const float* ch_w1 = (const float*)d_in[25];
    const float* ch_b1 = (const float*)d_in[26];
    const float* ch_w2 = (const float*)d_in[27];
    const float* ch_b2 = (const float*)d_in[28];

    float* out = (float*)d_out;
    const size_t OUT_IMG = (size_t)B * NC * OUT_HW * OUT_HW;  // 3145728
    const size_t HIDSZ = (size_t)B * NK * HW;                 // 4194304
    float* hid_out = out + OUT_IMG;
    float* cell_out = out + OUT_IMG + HIDSZ;

    float* ws = (float*)d_ws;
    const size_t XCAT = (size_t)B * CIN * HW;  // 4390912
    float* xcatA = ws;            ws += XCAT;
    float* xcatB = ws;            ws += XCAT;
    float* offb = ws;             ws += (size_t)B * 18 * HW;
    float* maskb = ws;            ws += (size_t)B * 9 * HW;
    unsigned short* apk[3];
    for (int i = 0; i < 3; i++) { apk[i] = (unsigned short*)ws; ws += 108 * 512 / 2; }
    unsigned short* apkOM[3];
    for (int i = 0; i < 3; i++) { apkOM[i] = (unsigned short*)ws; ws += 54 * 512 / 2; }
    float* y3 = ws;               ws += (size_t)B * NC * HW;
    float* pooled = ws;           ws += 16;
    float* chbuf = ws;            ws += (size_t)B * S2 * NC * K2;

    dim3 blk(256);
    dim3 g1(B * HW / 256);        // 256 blocks
    dim3 g4(B * HW / 256, 4);
    dim3 g3(B * HW / 256, 3);
    dim3 gd(B * HW / 64);         // 1024 strips (offmask)
    dim3 gd2(B * HW / 32);        // 2048 strips (split-K deform)

    k_lstm<<<g4, blk, 0, stream>>>(X, lstm_w, lstm_b, xcatA, hid_out, cell_out);
    k_copy_lr<<<g1, blk, 0, stream>>>(X, xcatA, xcatB);
    for (int i = 0; i < 3; i++) {
        k_prepA<<<dim3(108), dim3(512), 0, stream>>>(dw[i], apk[i]);
        k_prepOM<<<dim3(54), dim3(512), 0, stream>>>(ow[i], mw[i], apkOM[i]);
    }

    // layer 1: xcatA -> xcatB
    k_offmask<<<gd, blk, 0, stream>>>(xcatA, apkOM[0], ob[0], mb[0], offb, maskb);
    k_deform<<<gd2, blk, 0, stream>>>(xcatA, offb, maskb, apk[0], db[0], xcatB);
    // layer 2: xcatB -> xcatA
    k_offmask<<<gd, blk, 0, stream>>>(xcatB, apkOM[1], ob[1], mb[1], offb, maskb);
    k_deform<<<gd2, blk, 0, stream>>>(xcatB, offb, maskb, apk[1], db[1], xcatA);
    // layer 3: xcatA -> xcatB
    k_offmask<<<gd, blk, 0, stream>>>(xcatA, apkOM[2], ob[2], mb[2], offb, maskb);
    k_deform<<<gd2, blk, 0, stream>>>(xcatA, offb, maskb, apk[2], db[2], xcatB);

    k_conv3<<<g3, blk, 0, stream>>>(xcatB, conv_w, conv_b, y3);
    k_pool<<<dim3(B * NC), blk, 0, stream>>>(y3, pooled);
    k_ch<<<dim3(1), dim3(64), 0, stream>>>(pooled, ch_w1, ch_b1, ch_w2, ch_b2, chbuf);
    k_ddf<<<g4, blk, 0, stream>>>(y3, sp_w, sp_b, chbuf, out);
}